// Round 11
// baseline (157.796 us; speedup 1.0000x reference)
//
#include <hip/hip_runtime.h>

// ResNeXt sparse-voxel block, MI355X. Round 11.
// sconv10: 8 gather chains per wave (4 waves x 8 fragments, TJ=512).
// r10 lesson: voxel indices are spatially RANDOM (rng.choice unsorted) ->
// no locality lever exists; r9: occupancy irrelevant. The only lever that
// ever paid is per-wave independent-chain depth (2->4 chains: 64->46 us).
// This round: 4->8 chains. No launch_bounds cap (r7 spill lesson: 32 AGPR
// acc + 32 y-frag VGPRs + addr ~ 100 regs; a cap would spill).

#define NN    65536
#define CIN   128
#define CPATH 32
#define NPATH 4
#define NK    27
#define TJ    512
#define NTILE (NN / TJ)    // 128

typedef __attribute__((ext_vector_type(8))) short bfx8;
typedef __attribute__((ext_vector_type(4))) float fx4;

__device__ __forceinline__ unsigned short f2bf(float f) {
    unsigned u = __builtin_bit_cast(unsigned, f);
    u += 0x7FFFu + ((u >> 16) & 1u);
    return (unsigned short)(u >> 16);
}
__device__ __forceinline__ float bf2f(unsigned short s) {
    return __builtin_bit_cast(float, (unsigned)s << 16);
}
__device__ __forceinline__ bfx8 pack_bf8(const float4 a, const float4 b) {
    union { unsigned short s[8]; bfx8 v; } u;
    u.s[0] = f2bf(a.x); u.s[1] = f2bf(a.y); u.s[2] = f2bf(a.z); u.s[3] = f2bf(a.w);
    u.s[4] = f2bf(b.x); u.s[5] = f2bf(b.y); u.s[6] = f2bf(b.z); u.s[7] = f2bf(b.w);
    return u.v;
}

// ---------------------------------------------------------------------------
// wprep_rng: b<108: convW -> Wt[p][k][col][kin] bf16 (+ zero Hb sentinel row);
// b in [108,112): linW -> Wlt; b in [112,116): finW -> Wft;
// b >= 116: rngAll[pk][tile] = searchsorted(out_k, tile*TJ), tile=0..NTILE.
// ---------------------------------------------------------------------------
__global__ void wprep_rng(const float* __restrict__ convW,
                          const float* __restrict__ linW,
                          const float* __restrict__ finW,
                          const int* __restrict__ om,
                          unsigned short* __restrict__ Wt,
                          unsigned short* __restrict__ Wlt,
                          unsigned short* __restrict__ Wft,
                          unsigned short* __restrict__ Hb,
                          int* __restrict__ rngAll) {
    const int b = blockIdx.x;
    const int t = threadIdx.x;
    if (b < 108) {
        if (b == 0 && t < 64)
            ((unsigned*)(Hb + (size_t)NN * CIN))[t] = 0u;
        const int m = t >> 3;
        const int c0 = (t & 7) * 4;
        const float4 w = *(const float4*)(convW + ((size_t)b * CPATH + m) * CPATH + c0);
        unsigned short* o = Wt + (size_t)b * CPATH * CPATH;
        o[(c0 + 0) * CPATH + m] = f2bf(w.x);
        o[(c0 + 1) * CPATH + m] = f2bf(w.y);
        o[(c0 + 2) * CPATH + m] = f2bf(w.z);
        o[(c0 + 3) * CPATH + m] = f2bf(w.w);
    } else if (b < 112) {
        const int col = (b - 108) * 32 + (t >> 3);
        const int p = col >> 5, c = col & 31;
        const int k0 = (t & 7) * 16;
        for (int k = k0; k < k0 + 16; k++)
            Wlt[col * CIN + k] = f2bf(linW[(size_t)p * CIN * CPATH + k * CPATH + c]);
    } else if (b < 116) {
        const int col = (b - 112) * 32 + (t >> 3);
        const int k0 = (t & 7) * 16;
        for (int k = k0; k < k0 + 16; k++)
            Wft[col * CIN + k] = f2bf(finW[(size_t)k * CIN + col]);
    } else {
        const int idx = (b - 116) * 256 + t;     // pk*(NTILE+1) + tile
        if (idx < NPATH * NK * (NTILE + 1)) {
            const int tile = idx % (NTILE + 1);
            const int pk = idx / (NTILE + 1);
            const int bound = tile * TJ;
            const int* o = om + (size_t)pk * NN;
            int lo = 0, hi = NN;
            while (lo < hi) {
                const int mid = (lo + hi) >> 1;
                if (o[mid] < bound) lo = mid + 1; else hi = mid;
            }
            rngAll[idx] = lo;
        }
    }
}

// ---------------------------------------------------------------------------
// lin_mfma: Hb[row][c] = bf16(feats[row] @ Wcat[:,c] + linb[c]).
// ---------------------------------------------------------------------------
__global__ void __launch_bounds__(256, 4)
lin_mfma(const float* __restrict__ feats,
         const unsigned short* __restrict__ Wlt,
         const float* __restrict__ linb,
         unsigned short* __restrict__ Hb) {
    const int tid = threadIdx.x;
    const int w = tid >> 6, lane = tid & 63;
    const int mrow = lane & 15, kq = lane >> 4;
    const int row = blockIdx.x * 64 + w * 16 + mrow;

    fx4 acc[8];
#pragma unroll
    for (int g = 0; g < 8; g++) acc[g] = (fx4){0.f, 0.f, 0.f, 0.f};

#pragma unroll
    for (int kt = 0; kt < 4; ++kt) {
        const float4 y0 = *(const float4*)(feats + (size_t)row * CIN + kt * 32 + kq * 8);
        const float4 y1 = *(const float4*)(feats + (size_t)row * CIN + kt * 32 + kq * 8 + 4);
        const bfx8 yf = pack_bf8(y0, y1);
#pragma unroll
        for (int g = 0; g < 8; g++) {
            const bfx8 xf = *(const bfx8*)(Wlt + (size_t)(g * 16 + mrow) * CIN + kt * 32 + kq * 8);
            acc[g] = __builtin_amdgcn_mfma_f32_16x16x32_bf16(xf, yf, acc[g], 0, 0, 0);
        }
    }
#pragma unroll
    for (int g = 0; g < 8; g++) {
        const int c0 = g * 16 + kq * 4;
        const float4 bb = *(const float4*)(linb + c0);
        union { unsigned short s[4]; ushort4 v; } u;
        u.s[0] = f2bf(acc[g][0] + bb.x);
        u.s[1] = f2bf(acc[g][1] + bb.y);
        u.s[2] = f2bf(acc[g][2] + bb.z);
        u.s[3] = f2bf(acc[g][3] + bb.w);
        *(ushort4*)(Hb + (size_t)row * CIN + c0) = u.v;
    }
}

// ---------------------------------------------------------------------------
// sconv10: TJ=512, 256 thr = 4 waves x 8 fragments (8 independent gather
// chains per wave). Branchless dense-k, register accumulation, precomputed
// rng, fused BN partials, bf16 out. XCD-chunked tile swizzle retained.
// ---------------------------------------------------------------------------
__global__ void __launch_bounds__(256)
sconv10(const unsigned short* __restrict__ Hb,
        const unsigned short* __restrict__ Wt,
        const int* __restrict__ im,
        const int* __restrict__ om,
        const int* __restrict__ rngAll,
        unsigned short* __restrict__ Cbh,
        float* __restrict__ part) {
    __shared__ int idxT[TJ][29];      // odd stride: conflict-free column reads
    __shared__ int rng[NK][2];
    __shared__ float red[4][64];

    const int p = blockIdx.y;
    const int Traw = blockIdx.x;
    const int T = ((Traw & 7) << 4) | (Traw >> 3);   // XCD-chunked (NTILE=128)
    const int j0 = T * TJ;
    const int tid = threadIdx.x;
    const int w = tid >> 6, lane = tid & 63;
    const int mrow = lane & 15, kq = lane >> 4;

    for (int idx = tid; idx < TJ * 29; idx += 256)
        (&idxT[0][0])[idx] = NN;
    if (tid < NK * 2) {
        const int k = tid >> 1, which = tid & 1;
        rng[k][which] = rngAll[((size_t)p * NK + k) * (NTILE + 1) + T + which];
    }
    __syncthreads();
    {
        const int k = tid >> 3;
        if (k < NK) {
            const int s = rng[k][0], e = rng[k][1];
            const int* ok = om + ((size_t)p * NK + k) * NN;
            const int* ik = im + ((size_t)p * NK + k) * NN;
            for (int t = s + (tid & 7); t < e; t += 8)
                idxT[ok[t] - j0][k] = ik[t];
        }
    }
    __syncthreads();

    fx4 acc[8];
#pragma unroll
    for (int f = 0; f < 8; f++) acc[f] = (fx4){0.f, 0.f, 0.f, 0.f};

    const unsigned short* Wp = Wt + (size_t)p * NK * 1024 + kq * 8;
    const unsigned short* Hp = Hb + (size_t)p * CPATH + kq * 8;
    const int rb = w * 128 + mrow;

#pragma unroll 3
    for (int k = 0; k < NK; ++k) {
        const bfx8 x0 = *(const bfx8*)(Wp + (size_t)k * 1024 + mrow * CPATH);
        const bfx8 x1 = *(const bfx8*)(Wp + (size_t)k * 1024 + (16 + mrow) * CPATH);
        int iv[8];
#pragma unroll
        for (int f = 0; f < 8; f++) iv[f] = idxT[rb + f * 16][k];
        bfx8 y[8];
#pragma unroll
        for (int f = 0; f < 8; f++)
            y[f] = *(const bfx8*)(Hp + (size_t)iv[f] * CIN);
        // acc[f] holds channels (f&1 ? 16..31 : 0..15)?  No: keep per-frag
        // full 32ch in two halves folded into one fx4 pair per frag would
        // need 64 acc regs; instead each fragment accumulates 32 channels
        // via TWO mfma into acc pairs -> use 8 frags x 1 half + swap halves
        // per even/odd fragment would change layout. Keep both halves:
#pragma unroll
        for (int f = 0; f < 8; f += 2) {
            // even fragment f: channels 0..15; odd fragment f+1 shares y?
            // NOTE: to stay at 32 acc regs with 8 row-fragments we split the
            // channel halves across fragment parity is WRONG (rows differ).
            // Correct: 8 fragments x 2 halves needs 64 acc regs -- too many.
            // So: 8 chains but 16 channels per acc, second half handled by
            // a second MFMA into the SAME acc? No. We instead do both halves
            // sequentially below.
            (void)0;
        }
#pragma unroll
        for (int f = 0; f < 8; f++)
            acc[f] = __builtin_amdgcn_mfma_f32_16x16x32_bf16(x0, y[f], acc[f], 0, 0, 0);
#pragma unroll
        for (int f = 0; f < 8; f++)
            acc[f] = __builtin_amdgcn_mfma_f32_16x16x32_bf16(x1, y[f], acc[f], 0, 0, 0);
        // The two MFMAs above both accumulate into acc[f] with DIFFERENT
        // x-fragments -- that sums channel-half results, which is wrong
        // unless we separate outputs. Fix: alternate halves across k is
        // wrong too. => Use 8 fragments with half-channel split across
        // waves like sconv9? We instead split halves across the kq groups:
        // NOT POSSIBLE cleanly. Therefore: revert to separate acc halves,
        // 4 fragments of 2 halves + 4 more fragments of 2 halves = 16 fx4.
    }
    // --- The above block is structurally wrong; real implementation below
    // replaces this kernel entirely. (Kept unreachable-free: see sconv10b.)
    (void)acc; (void)part; (void)Cbh;
}

// ---------------------------------------------------------------------------
// sconv10b: the actual 8-chain kernel. 8 row-fragments x full 32 channels
// needs 64 fx4 acc -> too many regs. Compromise: 8 chains x 16 channels,
// channel half assigned per-WAVE (like sconv9): 8 waves per tile via
// gridDim.z=2 channel-halves. TJ=512, 4 waves/block, block handles one
// channel half of 512 rows with 8 chains/wave. 32 acc + 32 y + 4 x ~ 100 regs.
// ---------------------------------------------------------------------------
__global__ void __launch_bounds__(256)
sconv10b(const unsigned short* __restrict__ Hb,
         const unsigned short* __restrict__ Wt,
         const int* __restrict__ im,
         const int* __restrict__ om,
         const int* __restrict__ rngAll,
         unsigned short* __restrict__ Cbh,
         float* __restrict__ part) {
    __shared__ int idxT[TJ][29];
    __shared__ int rng[NK][2];
    __shared__ float red[4][32];

    const int p = blockIdx.y;
    const int hs = blockIdx.z;                        // channel half
    const int Traw = blockIdx.x;
    const int T = ((Traw & 7) << 4) | (Traw >> 3);    // XCD-chunked
    const int j0 = T * TJ;
    const int tid = threadIdx.x;
    const int w = tid >> 6, lane = tid & 63;
    const int mrow = lane & 15, kq = lane >> 4;

    for (int idx = tid; idx < TJ * 29; idx += 256)
        (&idxT[0][0])[idx] = NN;
    if (tid < NK * 2) {
        const int k = tid >> 1, which = tid & 1;
        rng[k][which] = rngAll[((size_t)p * NK + k) * (NTILE + 1) + T + which];
    }
    __syncthreads();
    {
        const int k = tid >> 3;
        if (k < NK) {
            const int s = rng[k][0], e = rng[k][1];
            const int* ok = om + ((size_t)p * NK + k) * NN;
            const int* ik = im + ((size_t)p * NK + k) * NN;
            for (int t = s + (tid & 7); t < e; t += 8)
                idxT[ok[t] - j0][k] = ik[t];
        }
    }
    __syncthreads();

    fx4 acc[8];
#pragma unroll
    for (int f = 0; f < 8; f++) acc[f] = (fx4){0.f, 0.f, 0.f, 0.f};

    // x-frag rows = output channels hs*16 + mrow
    const unsigned short* Wp = Wt + (size_t)p * NK * 1024 + (hs * 16 + mrow) * CPATH + kq * 8;
    const unsigned short* Hp = Hb + (size_t)p * CPATH + kq * 8;
    const int rb = w * 128 + mrow;

#pragma unroll 3
    for (int k = 0; k < NK; ++k) {
        const bfx8 x = *(const bfx8*)(Wp + (size_t)k * 1024);
        int iv[8];
#pragma unroll
        for (int f = 0; f < 8; f++) iv[f] = idxT[rb + f * 16][k];
        bfx8 y[8];
#pragma unroll
        for (int f = 0; f < 8; f++)
            y[f] = *(const bfx8*)(Hp + (size_t)iv[f] * CIN);
#pragma unroll
        for (int f = 0; f < 8; f++)
            acc[f] = __builtin_amdgcn_mfma_f32_16x16x32_bf16(x, y[f], acc[f], 0, 0, 0);
    }

    // BN partials: lane holds channels c = hs*16 + kq*4 + r (sum over rows)
    {
        float s[4], q[4];
#pragma unroll
        for (int r = 0; r < 4; r++) {
            float sv = 0.f, qv = 0.f;
#pragma unroll
            for (int f = 0; f < 8; f++) {
                const float v = acc[f][r];
                sv += v;
                qv = fmaf(v, v, qv);
            }
            s[r] = sv; q[r] = qv;
        }
#pragma unroll
        for (int m = 1; m < 16; m <<= 1)
#pragma unroll
            for (int r = 0; r < 4; r++) {
                s[r] += __shfl_xor(s[r], m, 64);
                q[r] += __shfl_xor(q[r], m, 64);
            }
        if (mrow == 0) {
#pragma unroll
            for (int r = 0; r < 4; r++) {
                const int c = kq * 4 + r;          // 0..15 within half
                red[w][c] = s[r];
                red[w][16 + c] = q[r];
            }
        }
    }
    __syncthreads();
    if (tid < 32) {
        const float sum = red[0][tid] + red[1][tid] + red[2][tid] + red[3][tid];
        // layout: part[(p*NTILE+T)*64 + hs*16 + (tid<16 ? tid : 16+...)]
        const int c = (tid & 15) + hs * 16;        // channel within path
        const int off = (tid < 16) ? 0 : 32;       // sum vs sumsq
        part[(((size_t)p * NTILE) + T) * 64 + off + c] = sum;
    }

    // writeback bf16: row = j0 + w*128 + f*16 + mrow, channels hs*16+kq*4..+3
#pragma unroll
    for (int f = 0; f < 8; f++) {
        const int row = j0 + w * 128 + f * 16 + mrow;
        union { unsigned short s[4]; ushort4 v; } u;
        u.s[0] = f2bf(acc[f][0]);
        u.s[1] = f2bf(acc[f][1]);
        u.s[2] = f2bf(acc[f][2]);
        u.s[3] = f2bf(acc[f][3]);
        *(ushort4*)(Cbh + (size_t)row * CIN + p * CPATH + hs * 16 + kq * 4) = u.v;
    }
}

// ---------------------------------------------------------------------------
// BN finalize, parallel: 512 thr = 4 tile-chunks x 128 channels.
// ---------------------------------------------------------------------------
__global__ void bn_stats2(const float* __restrict__ part,
                          const float* __restrict__ gamma,
                          const float* __restrict__ beta,
                          float* __restrict__ ss) {
    __shared__ float rs[4][128], rq[4][128];
    const int c = threadIdx.x & 127;
    const int ch = threadIdx.x >> 7;      // 0..3
    const int p = c >> 5, cc = c & 31;
    float s = 0.f, s2 = 0.f;
    for (int t = ch * (NTILE / 4); t < (ch + 1) * (NTILE / 4); t++) {
        s += part[(((size_t)p * NTILE) + t) * 64 + cc];
        s2 += part[(((size_t)p * NTILE) + t) * 64 + 32 + cc];
    }
    rs[ch][c] = s;
    rq[ch][c] = s2;
    __syncthreads();
    if (ch == 0) {
        s = rs[0][c] + rs[1][c] + rs[2][c] + rs[3][c];
        s2 = rq[0][c] + rq[1][c] + rq[2][c] + rq[3][c];
        const float mean = s * (1.f / NN);
        const float var = s2 * (1.f / NN) - mean * mean;
        const float sc = gamma[c] * rsqrtf(var + 1e-5f);
        ss[c] = sc;
        ss[128 + c] = beta[c] - mean * sc;
    }
}

// ---------------------------------------------------------------------------
// fin_mfma: out = relu(norm(Cbh)) @ finW + finb + feats.
// ---------------------------------------------------------------------------
__global__ void __launch_bounds__(256, 4)
fin_mfma(const unsigned short* __restrict__ Cbh,
         const float* __restrict__ ss,
         const unsigned short* __restrict__ Wft,
         const float* __restrict__ finb,
         const float* __restrict__ feats,
         float* __restrict__ out) {
    const int tid = threadIdx.x;
    const int w = tid >> 6, lane = tid & 63;
    const int mrow = lane & 15, kq = lane >> 4;
    const int row = blockIdx.x * 64 + w * 16 + mrow;

    fx4 acc[8];
#pragma unroll
    for (int g = 0; g < 8; g++) acc[g] = (fx4){0.f, 0.f, 0.f, 0.f};

#pragma unroll
    for (int kt = 0; kt < 4; ++kt) {
        const int k0 = kt * 32 + kq * 8;
        union { unsigned short s[8]; bfx8 v; } cb;
        cb.v = *(const bfx8*)(Cbh + (size_t)row * CIN + k0);
        const float4 sc0 = *(const float4*)(ss + k0);
        const float4 sc1 = *(const float4*)(ss + k0 + 4);
        const float4 sh0 = *(const float4*)(ss + 128 + k0);
        const float4 sh1 = *(const float4*)(ss + 128 + k0 + 4);
        float4 a, b;
        a.x = fmaxf(fmaf(bf2f(cb.s[0]), sc0.x, sh0.x), 0.f);
        a.y = fmaxf(fmaf(bf2f(cb.s[1]), sc0.y, sh0.y), 0.f);
        a.z = fmaxf(fmaf(bf2f(cb.s[2]), sc0.z, sh0.z), 0.f);
        a.w = fmaxf(fmaf(bf2f(cb.s[3]), sc0.w, sh0.w), 0.f);
        b.x = fmaxf(fmaf(bf2f(cb.s[4]), sc1.x, sh1.x), 0.f);
        b.y = fmaxf(fmaf(bf2f(cb.s[5]), sc1.y, sh1.y), 0.f);
        b.z = fmaxf(fmaf(bf2f(cb.s[6]), sc1.z, sh1.z), 0.f);
        b.w = fmaxf(fmaf(bf2f(cb.s[7]), sc1.w, sh1.w), 0.f);
        const bfx8 yf = pack_bf8(a, b);
#pragma unroll
        for (int g = 0; g < 8; g++) {
            const bfx8 xf = *(const bfx8*)(Wft + (size_t)(g * 16 + mrow) * CIN + kt * 32 + kq * 8);
            acc[g] = __builtin_amdgcn_mfma_f32_16x16x32_bf16(xf, yf, acc[g], 0, 0, 0);
        }
    }
#pragma unroll
    for (int g = 0; g < 8; g++) {
        const int c0 = g * 16 + kq * 4;
        const float4 fb = *(const float4*)(finb + c0);
        const float4 rs = *(const float4*)(feats + (size_t)row * CIN + c0);
        float4 o;
        o.x = acc[g][0] + fb.x + rs.x;
        o.y = acc[g][1] + fb.y + rs.y;
        o.z = acc[g][2] + fb.z + rs.z;
        o.w = acc[g][3] + fb.w + rs.w;
        *(float4*)(out + (size_t)row * CIN + c0) = o;
    }
}

// ---------------------------------------------------------------------------
extern "C" void kernel_launch(void* const* d_in, const int* in_sizes, int n_in,
                              void* d_out, int out_size, void* d_ws,
                              size_t ws_size, hipStream_t stream) {
    (void)in_sizes; (void)n_in; (void)out_size; (void)ws_size;
    const float* feats = (const float*)d_in[0];
    const float* linW  = (const float*)d_in[1];
    const float* linb  = (const float*)d_in[2];
    const float* convW = (const float*)d_in[3];
    const float* gamma = (const float*)d_in[4];
    const float* beta  = (const float*)d_in[5];
    const float* finW  = (const float*)d_in[6];
    const float* finb  = (const float*)d_in[7];
    const int*   im    = (const int*)d_in[8];
    const int*   om    = (const int*)d_in[9];
    float* out = (float*)d_out;

    char* ws = (char*)d_ws;
    unsigned short* Hb  = (unsigned short*)(ws);            // 16,781,312 (incl sentinel row + pad)
    unsigned short* Cbh = (unsigned short*)(ws + 16781312); // 16,777,216
    unsigned short* Wt  = (unsigned short*)(ws + 33558528); //    221,184
    unsigned short* Wlt = (unsigned short*)(ws + 33779712); //     32,768
    unsigned short* Wft = (unsigned short*)(ws + 33812480); //     32,768
    int*   rngAll       = (int*)(ws + 33845248);            //     55,728 -> pad 57,344
    float* part         = (float*)(ws + 33902592);          //    131,072
    float* ss           = (float*)(ws + 34033664);          //      1,024

    const int rng_total = NPATH * NK * (NTILE + 1);         // 13,932
    const int rng_blocks = (rng_total + 255) / 256;         // 55
    wprep_rng<<<116 + rng_blocks, 256, 0, stream>>>(convW, linW, finW, om,
                                                    Wt, Wlt, Wft, Hb, rngAll);
    lin_mfma<<<1024, 256, 0, stream>>>(feats, Wlt, linb, Hb);
    sconv10b<<<dim3(NTILE, NPATH, 2), 256, 0, stream>>>(Hb, Wt, im, om, rngAll, Cbh, part);
    bn_stats2<<<1, 512, 0, stream>>>(part, gamma, beta, ss);
    fin_mfma<<<1024, 256, 0, stream>>>(Cbh, ss, Wft, finb, feats, out);
}

// Round 12
// 93.677 us; speedup vs baseline: 1.6845x; 1.6845x over previous
//
#include <hip/hip_runtime.h>

// ResNeXt sparse-voxel block, MI355X. Round 12: compacted sparse conv with
// deterministic int32 LDS accumulation.
// Key insight: ~90% of the dense-k design's fragment-slots are sentinels
// (7.4% grid occupancy; only k=13 center is dense). Compaction needs
// scatter-accumulate; float atomics are order-dependent (nondeterministic),
// but INT atomics are associative -> accumulate contributions as fixed-point
// int32 (x 2^21) in LDS via atomicAdd. 16-entry groups straight from the
// sorted pair lists (coalesced), 2 MFMA per group, ~8x less conv work.

#define NN    65536
#define CIN   128
#define CPATH 32
#define NPATH 4
#define NK    27
#define TJ    512
#define NTILE (NN / TJ)    // 128
#define MAXG  288
#define SCALE_F 2097152.0f          // 2^21
#define INV_SCALE 4.76837158203125e-7f

typedef __attribute__((ext_vector_type(8))) short bfx8;
typedef __attribute__((ext_vector_type(4))) float fx4;

__device__ __forceinline__ unsigned short f2bf(float f) {
    unsigned u = __builtin_bit_cast(unsigned, f);
    u += 0x7FFFu + ((u >> 16) & 1u);
    return (unsigned short)(u >> 16);
}
__device__ __forceinline__ float bf2f(unsigned short s) {
    return __builtin_bit_cast(float, (unsigned)s << 16);
}
__device__ __forceinline__ bfx8 pack_bf8(const float4 a, const float4 b) {
    union { unsigned short s[8]; bfx8 v; } u;
    u.s[0] = f2bf(a.x); u.s[1] = f2bf(a.y); u.s[2] = f2bf(a.z); u.s[3] = f2bf(a.w);
    u.s[4] = f2bf(b.x); u.s[5] = f2bf(b.y); u.s[6] = f2bf(b.z); u.s[7] = f2bf(b.w);
    return u.v;
}

// ---------------------------------------------------------------------------
// wprep_rng: b<108: convW -> Wt[p][k][col][kin] bf16 (+ zero Hb sentinel row);
// b in [108,112): linW -> Wlt; b in [112,116): finW -> Wft;
// b >= 116: rngAll[pk][tile] = searchsorted(out_k, tile*TJ), tile=0..NTILE.
// ---------------------------------------------------------------------------
__global__ void wprep_rng(const float* __restrict__ convW,
                          const float* __restrict__ linW,
                          const float* __restrict__ finW,
                          const int* __restrict__ om,
                          unsigned short* __restrict__ Wt,
                          unsigned short* __restrict__ Wlt,
                          unsigned short* __restrict__ Wft,
                          unsigned short* __restrict__ Hb,
                          int* __restrict__ rngAll) {
    const int b = blockIdx.x;
    const int t = threadIdx.x;
    if (b < 108) {
        if (b == 0 && t < 64)
            ((unsigned*)(Hb + (size_t)NN * CIN))[t] = 0u;
        const int m = t >> 3;
        const int c0 = (t & 7) * 4;
        const float4 w = *(const float4*)(convW + ((size_t)b * CPATH + m) * CPATH + c0);
        unsigned short* o = Wt + (size_t)b * CPATH * CPATH;
        o[(c0 + 0) * CPATH + m] = f2bf(w.x);
        o[(c0 + 1) * CPATH + m] = f2bf(w.y);
        o[(c0 + 2) * CPATH + m] = f2bf(w.z);
        o[(c0 + 3) * CPATH + m] = f2bf(w.w);
    } else if (b < 112) {
        const int col = (b - 108) * 32 + (t >> 3);
        const int p = col >> 5, c = col & 31;
        const int k0 = (t & 7) * 16;
        for (int k = k0; k < k0 + 16; k++)
            Wlt[col * CIN + k] = f2bf(linW[(size_t)p * CIN * CPATH + k * CPATH + c]);
    } else if (b < 116) {
        const int col = (b - 112) * 32 + (t >> 3);
        const int k0 = (t & 7) * 16;
        for (int k = k0; k < k0 + 16; k++)
            Wft[col * CIN + k] = f2bf(finW[(size_t)k * CIN + col]);
    } else {
        const int idx = (b - 116) * 256 + t;     // pk*(NTILE+1) + tile
        if (idx < NPATH * NK * (NTILE + 1)) {
            const int tile = idx % (NTILE + 1);
            const int pk = idx / (NTILE + 1);
            const int bound = tile * TJ;
            const int* o = om + (size_t)pk * NN;
            int lo = 0, hi = NN;
            while (lo < hi) {
                const int mid = (lo + hi) >> 1;
                if (o[mid] < bound) lo = mid + 1; else hi = mid;
            }
            rngAll[idx] = lo;
        }
    }
}

// ---------------------------------------------------------------------------
// lin_mfma: Hb[row][c] = bf16(feats[row] @ Wcat[:,c] + linb[c]).
// ---------------------------------------------------------------------------
__global__ void __launch_bounds__(256, 4)
lin_mfma(const float* __restrict__ feats,
         const unsigned short* __restrict__ Wlt,
         const float* __restrict__ linb,
         unsigned short* __restrict__ Hb) {
    const int tid = threadIdx.x;
    const int w = tid >> 6, lane = tid & 63;
    const int mrow = lane & 15, kq = lane >> 4;
    const int row = blockIdx.x * 64 + w * 16 + mrow;

    fx4 acc[8];
#pragma unroll
    for (int g = 0; g < 8; g++) acc[g] = (fx4){0.f, 0.f, 0.f, 0.f};

#pragma unroll
    for (int kt = 0; kt < 4; ++kt) {
        const float4 y0 = *(const float4*)(feats + (size_t)row * CIN + kt * 32 + kq * 8);
        const float4 y1 = *(const float4*)(feats + (size_t)row * CIN + kt * 32 + kq * 8 + 4);
        const bfx8 yf = pack_bf8(y0, y1);
#pragma unroll
        for (int g = 0; g < 8; g++) {
            const bfx8 xf = *(const bfx8*)(Wlt + (size_t)(g * 16 + mrow) * CIN + kt * 32 + kq * 8);
            acc[g] = __builtin_amdgcn_mfma_f32_16x16x32_bf16(xf, yf, acc[g], 0, 0, 0);
        }
    }
#pragma unroll
    for (int g = 0; g < 8; g++) {
        const int c0 = g * 16 + kq * 4;
        const float4 bb = *(const float4*)(linb + c0);
        union { unsigned short s[4]; ushort4 v; } u;
        u.s[0] = f2bf(acc[g][0] + bb.x);
        u.s[1] = f2bf(acc[g][1] + bb.y);
        u.s[2] = f2bf(acc[g][2] + bb.z);
        u.s[3] = f2bf(acc[g][3] + bb.w);
        *(ushort4*)(Hb + (size_t)row * CIN + c0) = u.v;
    }
}

// ---------------------------------------------------------------------------
// sconv12: compacted sparse conv, deterministic int32 LDS accumulation.
// Per (p, 512-row tile): build group list (16 entries/group, per-k padded),
// 8 waves process 2 groups/iter; D lane mrow = entry -> jj local to lane.
// ---------------------------------------------------------------------------
__global__ void __launch_bounds__(512)
sconv12(const unsigned short* __restrict__ Hb,
        const unsigned short* __restrict__ Wt,
        const int* __restrict__ im,
        const int* __restrict__ om,
        const int* __restrict__ rngAll,
        unsigned short* __restrict__ Cbh,
        float* __restrict__ part) {
    __shared__ int accI[TJ + 1][33];      // +1 dump row; stride 33 = bank-safe
    __shared__ int rng[NK][2];
    __shared__ int gkA[MAXG], gtA[MAXG];
    __shared__ int gbase[NK];
    __shared__ int Gs;
    __shared__ float redS[16][32], redQ[16][32];

    const int p = blockIdx.y;
    const int T = blockIdx.x;
    const int j0 = T * TJ;
    const int tid = threadIdx.x;
    const int lane = tid & 63;
    const int w = tid >> 6;
    const int mrow = lane & 15, kq = lane >> 4;

    for (int idx = tid; idx < (TJ + 1) * 33; idx += 512)
        (&accI[0][0])[idx] = 0;
    if (tid < NK * 2) {
        const int k = tid >> 1, which = tid & 1;
        rng[k][which] = rngAll[((size_t)p * NK + k) * (NTILE + 1) + T + which];
    }
    __syncthreads();
    if (tid == 0) {
        int sum = 0;
#pragma unroll
        for (int k = 0; k < NK; k++) {
            gbase[k] = sum;
            sum += (rng[k][1] - rng[k][0] + 15) >> 4;
        }
        Gs = sum;
    }
    __syncthreads();
    if (tid < NK) {
        const int k = tid;
        const int s = rng[k][0];
        const int n = (rng[k][1] - s + 15) >> 4;
        const int b = gbase[k];
        for (int g = 0; g < n; g++) {
            gkA[b + g] = k;
            gtA[b + g] = s + g * 16;
        }
    }
    __syncthreads();

    const int G = Gs;
    const unsigned short* Wp = Wt + (size_t)p * NK * 1024 + kq * 8;
    const unsigned short* Hp = Hb + (size_t)p * CPATH + kq * 8;
    const int* omP = om + (size_t)p * NK * NN;
    const int* imP = im + (size_t)p * NK * NN;
    const fx4 z4 = {0.f, 0.f, 0.f, 0.f};

    for (int base = 2 * w; base < G; base += 16) {
        const int kA = gkA[base];
        const int tA = gtA[base] + mrow;
        int kB = 0, tB = NN + mrow;
        if (base + 1 < G) { kB = gkA[base + 1]; tB = gtA[base + 1] + mrow; }
        const int eA = rng[kA][1], eB = rng[kB][1];
        const bool vA = tA < eA, vB = tB < eB;
        const int jjA = vA ? (omP[(size_t)kA * NN + tA] - j0) : TJ;
        const int iA  = vA ? imP[(size_t)kA * NN + tA] : NN;
        const int jjB = vB ? (omP[(size_t)kB * NN + tB] - j0) : TJ;
        const int iB  = vB ? imP[(size_t)kB * NN + tB] : NN;
        const bfx8 xA0 = *(const bfx8*)(Wp + (size_t)kA * 1024 + mrow * CPATH);
        const bfx8 xA1 = *(const bfx8*)(Wp + (size_t)kA * 1024 + (16 + mrow) * CPATH);
        const bfx8 xB0 = *(const bfx8*)(Wp + (size_t)kB * 1024 + mrow * CPATH);
        const bfx8 xB1 = *(const bfx8*)(Wp + (size_t)kB * 1024 + (16 + mrow) * CPATH);
        const bfx8 yA = *(const bfx8*)(Hp + (size_t)iA * CIN);
        const bfx8 yB = *(const bfx8*)(Hp + (size_t)iB * CIN);
        const fx4 dA0 = __builtin_amdgcn_mfma_f32_16x16x32_bf16(xA0, yA, z4, 0, 0, 0);
        const fx4 dA1 = __builtin_amdgcn_mfma_f32_16x16x32_bf16(xA1, yA, z4, 0, 0, 0);
        const fx4 dB0 = __builtin_amdgcn_mfma_f32_16x16x32_bf16(xB0, yB, z4, 0, 0, 0);
        const fx4 dB1 = __builtin_amdgcn_mfma_f32_16x16x32_bf16(xB1, yB, z4, 0, 0, 0);
        // lane (mrow,kq) holds entry mrow's channels kq*4+r (d*0) / 16+kq*4+r (d*1)
#pragma unroll
        for (int r = 0; r < 4; r++) {
            atomicAdd(&accI[jjA][kq * 4 + r],      (int)rintf(dA0[r] * SCALE_F));
            atomicAdd(&accI[jjA][16 + kq * 4 + r], (int)rintf(dA1[r] * SCALE_F));
            atomicAdd(&accI[jjB][kq * 4 + r],      (int)rintf(dB0[r] * SCALE_F));
            atomicAdd(&accI[jjB][16 + kq * 4 + r], (int)rintf(dB1[r] * SCALE_F));
        }
    }
    __syncthreads();

    // Phase C: int -> f32, BN partials, bf16 writeback. Deterministic order.
    {
        const int c = tid & 31;
        const int rg = tid >> 5;          // 0..15
        float s = 0.f, q = 0.f;
        for (int m = 0; m < TJ / 16; m++) {
            const int r = rg + 16 * m;
            const float f = (float)accI[r][c] * INV_SCALE;
            s += f;
            q = fmaf(f, f, q);
            Cbh[(size_t)(j0 + r) * CIN + p * CPATH + c] = f2bf(f);
        }
        redS[rg][c] = s;
        redQ[rg][c] = q;
    }
    __syncthreads();
    if (tid < 32) {
        float s = 0.f;
#pragma unroll
        for (int g = 0; g < 16; g++) s += redS[g][tid];
        part[(((size_t)p * NTILE) + T) * 64 + tid] = s;
    } else if (tid < 64) {
        const int c = tid - 32;
        float q = 0.f;
#pragma unroll
        for (int g = 0; g < 16; g++) q += redQ[g][c];
        part[(((size_t)p * NTILE) + T) * 64 + 32 + c] = q;
    }
}

// ---------------------------------------------------------------------------
// BN finalize, parallel: 512 thr = 4 tile-chunks x 128 channels.
// ---------------------------------------------------------------------------
__global__ void bn_stats2(const float* __restrict__ part,
                          const float* __restrict__ gamma,
                          const float* __restrict__ beta,
                          float* __restrict__ ss) {
    __shared__ float rs[4][128], rq[4][128];
    const int c = threadIdx.x & 127;
    const int ch = threadIdx.x >> 7;      // 0..3
    const int p = c >> 5, cc = c & 31;
    float s = 0.f, s2 = 0.f;
    for (int t = ch * (NTILE / 4); t < (ch + 1) * (NTILE / 4); t++) {
        s += part[(((size_t)p * NTILE) + t) * 64 + cc];
        s2 += part[(((size_t)p * NTILE) + t) * 64 + 32 + cc];
    }
    rs[ch][c] = s;
    rq[ch][c] = s2;
    __syncthreads();
    if (ch == 0) {
        s = rs[0][c] + rs[1][c] + rs[2][c] + rs[3][c];
        s2 = rq[0][c] + rq[1][c] + rq[2][c] + rq[3][c];
        const float mean = s * (1.f / NN);
        const float var = s2 * (1.f / NN) - mean * mean;
        const float sc = gamma[c] * rsqrtf(var + 1e-5f);
        ss[c] = sc;
        ss[128 + c] = beta[c] - mean * sc;
    }
}

// ---------------------------------------------------------------------------
// fin_mfma: out = relu(norm(Cbh)) @ finW + finb + feats.
// ---------------------------------------------------------------------------
__global__ void __launch_bounds__(256, 4)
fin_mfma(const unsigned short* __restrict__ Cbh,
         const float* __restrict__ ss,
         const unsigned short* __restrict__ Wft,
         const float* __restrict__ finb,
         const float* __restrict__ feats,
         float* __restrict__ out) {
    const int tid = threadIdx.x;
    const int w = tid >> 6, lane = tid & 63;
    const int mrow = lane & 15, kq = lane >> 4;
    const int row = blockIdx.x * 64 + w * 16 + mrow;

    fx4 acc[8];
#pragma unroll
    for (int g = 0; g < 8; g++) acc[g] = (fx4){0.f, 0.f, 0.f, 0.f};

#pragma unroll
    for (int kt = 0; kt < 4; ++kt) {
        const int k0 = kt * 32 + kq * 8;
        union { unsigned short s[8]; bfx8 v; } cb;
        cb.v = *(const bfx8*)(Cbh + (size_t)row * CIN + k0);
        const float4 sc0 = *(const float4*)(ss + k0);
        const float4 sc1 = *(const float4*)(ss + k0 + 4);
        const float4 sh0 = *(const float4*)(ss + 128 + k0);
        const float4 sh1 = *(const float4*)(ss + 128 + k0 + 4);
        float4 a, b;
        a.x = fmaxf(fmaf(bf2f(cb.s[0]), sc0.x, sh0.x), 0.f);
        a.y = fmaxf(fmaf(bf2f(cb.s[1]), sc0.y, sh0.y), 0.f);
        a.z = fmaxf(fmaf(bf2f(cb.s[2]), sc0.z, sh0.z), 0.f);
        a.w = fmaxf(fmaf(bf2f(cb.s[3]), sc0.w, sh0.w), 0.f);
        b.x = fmaxf(fmaf(bf2f(cb.s[4]), sc1.x, sh1.x), 0.f);
        b.y = fmaxf(fmaf(bf2f(cb.s[5]), sc1.y, sh1.y), 0.f);
        b.z = fmaxf(fmaf(bf2f(cb.s[6]), sc1.z, sh1.z), 0.f);
        b.w = fmaxf(fmaf(bf2f(cb.s[7]), sc1.w, sh1.w), 0.f);
        const bfx8 yf = pack_bf8(a, b);
#pragma unroll
        for (int g = 0; g < 8; g++) {
            const bfx8 xf = *(const bfx8*)(Wft + (size_t)(g * 16 + mrow) * CIN + kt * 32 + kq * 8);
            acc[g] = __builtin_amdgcn_mfma_f32_16x16x32_bf16(xf, yf, acc[g], 0, 0, 0);
        }
    }
#pragma unroll
    for (int g = 0; g < 8; g++) {
        const int c0 = g * 16 + kq * 4;
        const float4 fb = *(const float4*)(finb + c0);
        const float4 rs = *(const float4*)(feats + (size_t)row * CIN + c0);
        float4 o;
        o.x = acc[g][0] + fb.x + rs.x;
        o.y = acc[g][1] + fb.y + rs.y;
        o.z = acc[g][2] + fb.z + rs.z;
        o.w = acc[g][3] + fb.w + rs.w;
        *(float4*)(out + (size_t)row * CIN + c0) = o;
    }
}

// ---------------------------------------------------------------------------
extern "C" void kernel_launch(void* const* d_in, const int* in_sizes, int n_in,
                              void* d_out, int out_size, void* d_ws,
                              size_t ws_size, hipStream_t stream) {
    (void)in_sizes; (void)n_in; (void)out_size; (void)ws_size;
    const float* feats = (const float*)d_in[0];
    const float* linW  = (const float*)d_in[1];
    const float* linb  = (const float*)d_in[2];
    const float* convW = (const float*)d_in[3];
    const float* gamma = (const float*)d_in[4];
    const float* beta  = (const float*)d_in[5];
    const float* finW  = (const float*)d_in[6];
    const float* finb  = (const float*)d_in[7];
    const int*   im    = (const int*)d_in[8];
    const int*   om    = (const int*)d_in[9];
    float* out = (float*)d_out;

    char* ws = (char*)d_ws;
    unsigned short* Hb  = (unsigned short*)(ws);            // 16,781,312 (incl sentinel row + pad)
    unsigned short* Cbh = (unsigned short*)(ws + 16781312); // 16,777,216
    unsigned short* Wt  = (unsigned short*)(ws + 33558528); //    221,184
    unsigned short* Wlt = (unsigned short*)(ws + 33779712); //     32,768
    unsigned short* Wft = (unsigned short*)(ws + 33812480); //     32,768
    int*   rngAll       = (int*)(ws + 33845248);            //     55,728 -> pad 57,344
    float* part         = (float*)(ws + 33902592);          //    131,072
    float* ss           = (float*)(ws + 34033664);          //      1,024

    const int rng_total = NPATH * NK * (NTILE + 1);         // 13,932
    const int rng_blocks = (rng_total + 255) / 256;         // 55
    wprep_rng<<<116 + rng_blocks, 256, 0, stream>>>(convW, linW, finW, om,
                                                    Wt, Wlt, Wft, Hb, rngAll);
    lin_mfma<<<1024, 256, 0, stream>>>(feats, Wlt, linb, Hb);
    sconv12<<<dim3(NTILE, NPATH), 512, 0, stream>>>(Hb, Wt, im, om, rngAll, Cbh, part);
    bn_stats2<<<1, 512, 0, stream>>>(part, gamma, beta, ss);
    fin_mfma<<<1024, 256, 0, stream>>>(Cbh, ss, Wft, finb, feats, out);
}